// Round 6
// baseline (213.769 us; speedup 1.0000x reference)
//
#include <hip/hip_runtime.h>
#include <hip/hip_bf16.h>
#include <stdint.h>

#define B_ 4
#define T_ 8192
#define D_ 512
#define H_ 512
#define M_ (B_ * T_)          // 32768 rows
#define SEG 32                // scan segment length (t steps)
#define NSEG (M_ / SEG)       // 1024 segments total (256 per batch)

typedef __attribute__((ext_vector_type(8))) short short8;
typedef __attribute__((ext_vector_type(4))) float floatx4;

__device__ __forceinline__ unsigned short f2bf(float f) {
    union { float f; unsigned int u; } v; v.f = f;
    unsigned int u = v.u;
    u += 0x7fffu + ((u >> 16) & 1u);   // RNE
    return (unsigned short)(u >> 16);
}
__device__ __forceinline__ float bf_lo(unsigned int u) {
    union { unsigned int i; float f; } a; a.i = u << 16; return a.f;
}
__device__ __forceinline__ float bf_hi(unsigned int u) {
    union { unsigned int i; float f; } a; a.i = u & 0xffff0000u; return a.f;
}
__device__ __forceinline__ unsigned int pk_cd(float c, float d) {
    return (unsigned int)f2bf(c) | ((unsigned int)f2bf(d) << 16);
}

// ---------------------------------------------------------------------------
// fused f32 -> bf16 converter for x, Wz, Wh (one launch)
// ---------------------------------------------------------------------------
__global__ void conv_all(const float* __restrict__ x,
                         const float* __restrict__ Wz,
                         const float* __restrict__ Wh,
                         unsigned short* __restrict__ xbf,
                         unsigned short* __restrict__ Wf)
{
    const int X4 = M_ * D_ / 4;
    const int W4 = H_ * D_ / 4;
    int i = blockIdx.x * blockDim.x + threadIdx.x;
    const float* src; unsigned short* dst; int idx;
    if (i < X4)             { src = x;  dst = xbf;                  idx = i; }
    else if (i < X4 + W4)   { src = Wz; dst = Wf;                   idx = i - X4; }
    else if (i < X4 + 2*W4) { src = Wh; dst = Wf + (size_t)H_ * D_; idx = i - X4 - W4; }
    else return;
    float4 v = ((const float4*)src)[idx];
    ushort4 w; w.x = f2bf(v.x); w.y = f2bf(v.y); w.z = f2bf(v.z); w.w = f2bf(v.w);
    ((ushort4*)dst)[idx] = w;
}

// ---------------------------------------------------------------------------
// Dual GEMM (128m x 64h tile, z+h) + act epilogue + fused 32-t segment scan.
// Single-barrier LDS double-buffer K-loop: stage(k+1) issued after frag reads
// of k, one __syncthreads per iter -> loads in flight across the barrier gap.
// Epilogue: (c,d) bf16 pairs -> global cd + LDS transpose (stride 68 dwords,
// conflict-free) -> per-wave 32-t column scans -> Sagg[seg][h] = (C,D).
// ---------------------------------------------------------------------------
#define LDSB 35840     // union: 2x16 KB staging bufs | 128x68 dword cd tile (34816 B)

__global__ __launch_bounds__(256, 3)
void gemm_cd(const unsigned short* __restrict__ xbf,
             const unsigned short* __restrict__ Wf,   // rows [0:512)=Wz, [512:1024)=Wh
             const float* __restrict__ bz, const float* __restrict__ bh,
             unsigned int* __restrict__ cd,           // [M][512] (c,d) bf16-pair dwords
             float2* __restrict__ Sagg)               // [NSEG][512] (C,D)
{
    __shared__ __align__(16) char smem[LDSB];
    unsigned short* lds = (unsigned short*)smem;      // staging (shorts)
    unsigned int*   cdl = (unsigned int*)smem;        // cd transpose tile (dwords)

    const int tid  = threadIdx.x;
    const int lane = tid & 63;
    const int wave = tid >> 6;
    // grid = 2048: bits [2:0]=xcd, [5:3]=hblk(8), [10:6]=m-band(32)
    const int xcd  = blockIdx.x & 7;
    const int nblk = (blockIdx.x >> 3) & 7;
    const int mblk = xcd * 32 + (blockIdx.x >> 6);
    const int m0 = mblk * 128;
    const int n0 = nblk * 64;
    const int wm = (wave >> 1) * 64;
    const int wn = (wave & 1) * 32;
    const int l15  = lane & 15;
    const int quad = lane >> 4;
    const int srow = lane >> 2;
    const int sp   = lane & 3;

    // buf p base (shorts): p*8192 ; A at +0 (4096), Wz +4096 (2048), Wh +6144
    #define STAGE(p, kt)                                                          \
    {                                                                             \
        const int kb = (kt) * 32;                                                 \
        unsigned short* bb = lds + (p) * 8192;                                    \
        _Pragma("unroll")                                                         \
        for (int r = 0; r < 2; ++r) {                                             \
            const int chunk = r * 4 + wave;                                       \
            const int row   = chunk * 16 + srow;                                  \
            const int kp    = sp ^ (row & 3);                                     \
            __builtin_amdgcn_global_load_lds(                                     \
                (const __attribute__((address_space(1))) unsigned int*)           \
                    (xbf + (size_t)(m0 + row) * D_ + kb + kp * 8),                \
                (__attribute__((address_space(3))) unsigned int*)(bb + chunk * 512),\
                16, 0, 0);                                                        \
        }                                                                         \
        {                                                                         \
            const int row = wave * 16 + srow;                                     \
            const int kp  = sp ^ (row & 3);                                       \
            __builtin_amdgcn_global_load_lds(                                     \
                (const __attribute__((address_space(1))) unsigned int*)           \
                    (Wf + (size_t)(n0 + row) * D_ + kb + kp * 8),                 \
                (__attribute__((address_space(3))) unsigned int*)(bb + 4096 + wave * 512),\
                16, 0, 0);                                                        \
            __builtin_amdgcn_global_load_lds(                                     \
                (const __attribute__((address_space(1))) unsigned int*)           \
                    (Wf + (size_t)(512 + n0 + row) * D_ + kb + kp * 8),           \
                (__attribute__((address_space(3))) unsigned int*)(bb + 6144 + wave * 512),\
                16, 0, 0);                                                        \
        }                                                                         \
    }

    floatx4 acc_z[4][2], acc_h[4][2];
    #pragma unroll
    for (int i = 0; i < 4; ++i)
        #pragma unroll
        for (int j = 0; j < 2; ++j) { acc_z[i][j] = (floatx4)0.0f; acc_h[i][j] = (floatx4)0.0f; }

    STAGE(0, 0);

    for (int kt = 0; kt < 16; ++kt) {
        __syncthreads();   // drains loads(kt) [vmcnt] + protects buf reuse
        const int base = (kt & 1) * 8192;
        short8 af[4], zf[2], hf[2];
        #pragma unroll
        for (int i = 0; i < 4; ++i) {
            const int ra = wm + i * 16 + l15;
            af[i] = *(const short8*)&lds[base + ra * 32 + ((quad ^ (ra & 3)) * 8)];
        }
        #pragma unroll
        for (int j = 0; j < 2; ++j) {
            const int rb = wn + j * 16 + l15;
            zf[j] = *(const short8*)&lds[base + 4096 + rb * 32 + ((quad ^ (rb & 3)) * 8)];
            hf[j] = *(const short8*)&lds[base + 6144 + rb * 32 + ((quad ^ (rb & 3)) * 8)];
        }
        if (kt < 15) STAGE((kt + 1) & 1, kt + 1);   // in flight during MFMA + next barrier
        #pragma unroll
        for (int i = 0; i < 4; ++i)
            #pragma unroll
            for (int j = 0; j < 2; ++j) {
                // A=W frag (h side), B=x frag (m side): D row=h, D col=m
                acc_z[i][j] = __builtin_amdgcn_mfma_f32_16x16x32_bf16(zf[j], af[i], acc_z[i][j], 0, 0, 0);
                acc_h[i][j] = __builtin_amdgcn_mfma_f32_16x16x32_bf16(hf[j], af[i], acc_h[i][j], 0, 0, 0);
            }
    }

    __syncthreads();   // staging LDS dead; reuse as cd transpose tile

    // epilogue: m = m0+wm+i*16+l15 ; h = n0+wn+j*16+quad*4+r
    #pragma unroll
    for (int j = 0; j < 2; ++j) {
        const int hlb = wn + j * 16 + quad * 4;
        const float4 bzv = *(const float4*)&bz[n0 + hlb];
        const float4 bhv = *(const float4*)&bh[n0 + hlb];
        #pragma unroll
        for (int i = 0; i < 4; ++i) {
            const int mloc = wm + i * 16 + l15;
            uint4 w;
            #pragma unroll
            for (int r = 0; r < 4; ++r) {
                float kz = acc_z[i][j][r] + ((const float*)&bzv)[r];
                float hp = acc_h[i][j][r] + ((const float*)&bhv)[r];
                float c  = 1.0f / (1.0f + __expf(kz));   // sigmoid(-kz)
                float g  = (hp >= 0.0f) ? (hp + 0.5f) : (1.0f / (1.0f + __expf(-hp)));
                float d  = (1.0f - c) * g;
                ((unsigned int*)&w)[r] = pk_cd(c, d);
            }
            *(uint4*)&cd[(size_t)(m0 + mloc) * H_ + n0 + hlb] = w;
            *(uint4*)&cdl[mloc * 68 + hlb] = w;          // stride 68 -> conflict-free columns
        }
    }

    __syncthreads();

    // segment scans: wave = 32-t segment, lane = h column (64)
    {
        float C = 1.0f, Dv = 0.0f;
        const int t0 = wave * 32;
        #pragma unroll
        for (int t = 0; t < 32; ++t) {
            unsigned int u = cdl[(t0 + t) * 68 + lane];
            float c = bf_lo(u), d = bf_hi(u);
            Dv = fmaf(c, Dv, d);
            C *= c;
        }
        Sagg[(size_t)((m0 >> 5) + wave) * H_ + n0 + lane] = make_float2(C, Dv);
    }
    #undef STAGE
}

// ---------------------------------------------------------------------------
// inter-segment sequential scan: 2048 chains (b,h) x 256 segments
// ---------------------------------------------------------------------------
__global__ __launch_bounds__(256)
void interseg(const float* __restrict__ h_prev,
              const float2* __restrict__ Sagg,
              float* __restrict__ Hseg)
{
    const int flat = blockIdx.x * 256 + threadIdx.x;
    const int b = flat >> 9;
    const int h = flat & 511;
    float hs = h_prev[(size_t)b * H_ + h];
    #pragma unroll 8
    for (int s = 0; s < T_ / SEG; ++s) {
        size_t o = (size_t)(b * (T_ / SEG) + s) * H_ + h;
        Hseg[o] = hs;
        float2 cdv = Sagg[o];
        hs = fmaf(cdv.x, hs, cdv.y);
    }
}

// ---------------------------------------------------------------------------
// final apply: 2048 blocks = 1024 segments x 2 h-halves, 256 thr x 1 h
// ---------------------------------------------------------------------------
__global__ __launch_bounds__(256)
void apply_scan(const unsigned int* __restrict__ cd,
                const float* __restrict__ Hseg,
                float* __restrict__ out)
{
    const int sg   = blockIdx.x >> 1;
    const int half = blockIdx.x & 1;
    const int h = half * 256 + threadIdx.x;
    float hs = Hseg[(size_t)sg * H_ + h];
    const unsigned int* base = cd + (size_t)sg * SEG * H_ + h;
    float* ob = out + (size_t)sg * SEG * H_ + h;
    #pragma unroll 8
    for (int t = 0; t < SEG; ++t) {
        unsigned int u = base[(size_t)t * H_];
        hs = fmaf(bf_lo(u), hs, bf_hi(u));
        ob[(size_t)t * H_] = hs;
    }
}

// ---------------------------------------------------------------------------
extern "C" void kernel_launch(void* const* d_in, const int* in_sizes, int n_in,
                              void* d_out, int out_size, void* d_ws, size_t ws_size,
                              hipStream_t stream)
{
    const float* x      = (const float*)d_in[0];
    const float* h_prev = (const float*)d_in[1];
    const float* W_h    = (const float*)d_in[2];
    const float* b_h    = (const float*)d_in[3];
    const float* W_z    = (const float*)d_in[4];
    const float* b_z    = (const float*)d_in[5];
    float* out = (float*)d_out;

    // xbf lives in d_out (dead until apply_scan overwrites all of it)
    unsigned short* xbf = (unsigned short*)d_out;               // 33.5 MB < 67 MB out

    char* ws = (char*)d_ws;
    unsigned int* cd = (unsigned int*)ws;                       // M*H dwords = 67.1 MB
    size_t cd_bytes = (size_t)M_ * H_ * 4;
    unsigned short* Wf = (unsigned short*)(ws + cd_bytes);      // 1 MB
    size_t wf_bytes = (size_t)2 * H_ * D_ * sizeof(unsigned short);
    float2* Sagg = (float2*)(ws + cd_bytes + wf_bytes);         // NSEG*512*8 B = 4 MB
    float*  Hseg = (float*)(ws + cd_bytes + wf_bytes + (size_t)NSEG * H_ * sizeof(float2)); // 2 MB

    // 0) convert inputs to bf16
    {
        int total = M_ * D_ / 4 + 2 * (H_ * D_ / 4);
        conv_all<<<dim3((total + 255) / 256), dim3(256), 0, stream>>>(x, W_z, W_h, xbf, Wf);
    }
    // 1) dual GEMM + activation + fused segment aggregates
    gemm_cd<<<dim3((M_ / 128) * (H_ / 64)), dim3(256), 0, stream>>>(
        xbf, Wf, b_z, b_h, cd, Sagg);
    // 2) inter-segment sequential scan
    interseg<<<dim3(8), dim3(256), 0, stream>>>(h_prev, Sagg, Hseg);
    // 3) final apply -> d_out (overwrites xbf scratch)
    apply_scan<<<dim3(NSEG * 2), dim3(256), 0, stream>>>(cd, Hseg, out);
}

// Round 8
// 192.871 us; speedup vs baseline: 1.1084x; 1.1084x over previous
//
#include <hip/hip_runtime.h>
#include <hip/hip_bf16.h>
#include <stdint.h>

#define B_ 4
#define T_ 8192
#define D_ 512
#define H_ 512
#define M_ (B_ * T_)          // 32768 rows
#define SEG 32                // scan segment length (t steps)
#define SPB 256               // segments per batch chain (T_/SEG)
#define NSEG (M_ / SEG)       // 1024 segments total

typedef __attribute__((ext_vector_type(8))) short short8;
typedef __attribute__((ext_vector_type(4))) float floatx4;
typedef __attribute__((ext_vector_type(2))) unsigned int uint2e;
typedef __attribute__((ext_vector_type(2))) float float2e;

__device__ __forceinline__ unsigned short f2bf(float f) {
    union { float f; unsigned int u; } v; v.f = f;
    unsigned int u = v.u;
    u += 0x7fffu + ((u >> 16) & 1u);   // RNE
    return (unsigned short)(u >> 16);
}
__device__ __forceinline__ float bf_lo(unsigned int u) {
    union { unsigned int i; float f; } a; a.i = u << 16; return a.f;
}
__device__ __forceinline__ float bf_hi(unsigned int u) {
    union { unsigned int i; float f; } a; a.i = u & 0xffff0000u; return a.f;
}
__device__ __forceinline__ unsigned int pk_cd(float c, float d) {
    return (unsigned int)f2bf(c) | ((unsigned int)f2bf(d) << 16);
}

// ---------------------------------------------------------------------------
// fused f32 -> bf16 converter for x, Wz, Wh (one launch)
// ---------------------------------------------------------------------------
__global__ void conv_all(const float* __restrict__ x,
                         const float* __restrict__ Wz,
                         const float* __restrict__ Wh,
                         unsigned short* __restrict__ xbf,
                         unsigned short* __restrict__ Wf)
{
    const int X4 = M_ * D_ / 4;
    const int W4 = H_ * D_ / 4;
    int i = blockIdx.x * blockDim.x + threadIdx.x;
    const float* src; unsigned short* dst; int idx;
    if (i < X4)             { src = x;  dst = xbf;                  idx = i; }
    else if (i < X4 + W4)   { src = Wz; dst = Wf;                   idx = i - X4; }
    else if (i < X4 + 2*W4) { src = Wh; dst = Wf + (size_t)H_ * D_; idx = i - X4 - W4; }
    else return;
    float4 v = ((const float4*)src)[idx];
    ushort4 w; w.x = f2bf(v.x); w.y = f2bf(v.y); w.z = f2bf(v.z); w.w = f2bf(v.w);
    ((ushort4*)dst)[idx] = w;
}

// ---------------------------------------------------------------------------
// Dual GEMM (128m x 64h tile, z+h) + act epilogue + fused 32-t segment scan.
// Single-barrier LDS double-buffer K-loop. Sagg written CHAIN-MAJOR
// [b*512+h][256 segs] so interseg reads are fully coalesced.
// ---------------------------------------------------------------------------
#define LDSB 35840     // union: 2x16 KB staging bufs | 128x68 dword cd tile

__global__ __launch_bounds__(256, 3)
void gemm_cd(const unsigned short* __restrict__ xbf,
             const unsigned short* __restrict__ Wf,   // rows [0:512)=Wz, [512:1024)=Wh
             const float* __restrict__ bz, const float* __restrict__ bh,
             unsigned int* __restrict__ cd,           // [M][512] (c,d) bf16-pair dwords
             float2* __restrict__ Sagg)               // [2048 chains][256 segs]
{
    __shared__ __align__(16) char smem[LDSB];
    unsigned short* lds = (unsigned short*)smem;      // staging (shorts)
    unsigned int*   cdl = (unsigned int*)smem;        // cd transpose tile (dwords)

    const int tid  = threadIdx.x;
    const int lane = tid & 63;
    const int wave = tid >> 6;
    const int xcd  = blockIdx.x & 7;
    const int nblk = (blockIdx.x >> 3) & 7;
    const int mblk = xcd * 32 + (blockIdx.x >> 6);
    const int m0 = mblk * 128;
    const int n0 = nblk * 64;
    const int wm = (wave >> 1) * 64;
    const int wn = (wave & 1) * 32;
    const int l15  = lane & 15;
    const int quad = lane >> 4;
    const int srow = lane >> 2;
    const int sp   = lane & 3;

    #define STAGE(p, kt)                                                          \
    {                                                                             \
        const int kb = (kt) * 32;                                                 \
        unsigned short* bb = lds + (p) * 8192;                                    \
        _Pragma("unroll")                                                         \
        for (int r = 0; r < 2; ++r) {                                             \
            const int chunk = r * 4 + wave;                                       \
            const int row   = chunk * 16 + srow;                                  \
            const int kp    = sp ^ (row & 3);                                     \
            __builtin_amdgcn_global_load_lds(                                     \
                (const __attribute__((address_space(1))) unsigned int*)           \
                    (xbf + (size_t)(m0 + row) * D_ + kb + kp * 8),                \
                (__attribute__((address_space(3))) unsigned int*)(bb + chunk * 512),\
                16, 0, 0);                                                        \
        }                                                                         \
        {                                                                         \
            const int row = wave * 16 + srow;                                     \
            const int kp  = sp ^ (row & 3);                                       \
            __builtin_amdgcn_global_load_lds(                                     \
                (const __attribute__((address_space(1))) unsigned int*)           \
                    (Wf + (size_t)(n0 + row) * D_ + kb + kp * 8),                 \
                (__attribute__((address_space(3))) unsigned int*)(bb + 4096 + wave * 512),\
                16, 0, 0);                                                        \
            __builtin_amdgcn_global_load_lds(                                     \
                (const __attribute__((address_space(1))) unsigned int*)           \
                    (Wf + (size_t)(512 + n0 + row) * D_ + kb + kp * 8),           \
                (__attribute__((address_space(3))) unsigned int*)(bb + 6144 + wave * 512),\
                16, 0, 0);                                                        \
        }                                                                         \
    }

    floatx4 acc_z[4][2], acc_h[4][2];
    #pragma unroll
    for (int i = 0; i < 4; ++i)
        #pragma unroll
        for (int j = 0; j < 2; ++j) { acc_z[i][j] = (floatx4)0.0f; acc_h[i][j] = (floatx4)0.0f; }

    STAGE(0, 0);

    for (int kt = 0; kt < 16; ++kt) {
        __syncthreads();
        const int base = (kt & 1) * 8192;
        short8 af[4], zf[2], hf[2];
        #pragma unroll
        for (int i = 0; i < 4; ++i) {
            const int ra = wm + i * 16 + l15;
            af[i] = *(const short8*)&lds[base + ra * 32 + ((quad ^ (ra & 3)) * 8)];
        }
        #pragma unroll
        for (int j = 0; j < 2; ++j) {
            const int rb = wn + j * 16 + l15;
            zf[j] = *(const short8*)&lds[base + 4096 + rb * 32 + ((quad ^ (rb & 3)) * 8)];
            hf[j] = *(const short8*)&lds[base + 6144 + rb * 32 + ((quad ^ (rb & 3)) * 8)];
        }
        if (kt < 15) STAGE((kt + 1) & 1, kt + 1);
        #pragma unroll
        for (int i = 0; i < 4; ++i)
            #pragma unroll
            for (int j = 0; j < 2; ++j) {
                acc_z[i][j] = __builtin_amdgcn_mfma_f32_16x16x32_bf16(zf[j], af[i], acc_z[i][j], 0, 0, 0);
                acc_h[i][j] = __builtin_amdgcn_mfma_f32_16x16x32_bf16(hf[j], af[i], acc_h[i][j], 0, 0, 0);
            }
    }

    __syncthreads();   // staging LDS dead; reuse as cd transpose tile

    #pragma unroll
    for (int j = 0; j < 2; ++j) {
        const int hlb = wn + j * 16 + quad * 4;
        const float4 bzv = *(const float4*)&bz[n0 + hlb];
        const float4 bhv = *(const float4*)&bh[n0 + hlb];
        #pragma unroll
        for (int i = 0; i < 4; ++i) {
            const int mloc = wm + i * 16 + l15;
            uint4 w;
            #pragma unroll
            for (int r = 0; r < 4; ++r) {
                float kz = acc_z[i][j][r] + ((const float*)&bzv)[r];
                float hp = acc_h[i][j][r] + ((const float*)&bhv)[r];
                float c  = 1.0f / (1.0f + __expf(kz));   // sigmoid(-kz)
                float g  = (hp >= 0.0f) ? (hp + 0.5f) : (1.0f / (1.0f + __expf(-hp)));
                float d  = (1.0f - c) * g;
                ((unsigned int*)&w)[r] = pk_cd(c, d);
            }
            *(uint4*)&cd[(size_t)(m0 + mloc) * H_ + n0 + hlb] = w;
            *(uint4*)&cdl[mloc * 68 + hlb] = w;
        }
    }

    __syncthreads();

    // segment scans: wave = 32-t segment, lane = h column; chain-major store
    {
        float C = 1.0f, Dv = 0.0f;
        const int t0 = wave * 32;
        #pragma unroll
        for (int t = 0; t < 32; ++t) {
            unsigned int u = cdl[(t0 + t) * 68 + lane];
            float c = bf_lo(u), d = bf_hi(u);
            Dv = fmaf(c, Dv, d);
            C *= c;
        }
        const int chain = (m0 >> 13) * 512 + n0 + lane;      // b*512 + h
        const int seg   = ((m0 >> 5) & 255) + wave;          // in-batch segment
        Sagg[(size_t)chain * SPB + seg] = make_float2(C, Dv);
    }
    #undef STAGE
}

// ---------------------------------------------------------------------------
// inter-segment scan: one WAVE per (b,h) chain; lane l holds segs 4l..4l+3.
// Affine compose + 6-step shfl_up scan -> Hseg (chain-major, coalesced).
// 2048 chains = 512 blocks x 4 waves.
// ---------------------------------------------------------------------------
__global__ __launch_bounds__(256)
void interseg(const float* __restrict__ h_prev,
              const float2* __restrict__ Sagg,
              float* __restrict__ Hseg)
{
    const int chain = blockIdx.x * 4 + (threadIdx.x >> 6);
    const int lane  = threadIdx.x & 63;
    const float2* spp = Sagg + (size_t)chain * SPB + lane * 4;
    float4 q0 = *(const float4*)&spp[0];   // (C0,D0,C1,D1)
    float4 q1 = *(const float4*)&spp[2];   // (C2,D2,C3,D3)
    // lane-local composition in time order: m3∘m2∘m1∘m0
    float C = q0.x, D = q0.y;
    D = fmaf(q0.z, D, q0.w);  C *= q0.z;
    D = fmaf(q1.x, D, q1.y);  C *= q1.x;
    D = fmaf(q1.z, D, q1.w);  C *= q1.z;
    // inclusive wave scan (earlier lanes applied first)
    #pragma unroll
    for (int off = 1; off < 64; off <<= 1) {
        float Cp = __shfl_up(C, off, 64);
        float Dp = __shfl_up(D, off, 64);
        if (lane >= off) { D = fmaf(C, Dp, D); C *= Cp; }
    }
    // exclusive
    float Ce = __shfl_up(C, 1, 64);
    float De = __shfl_up(D, 1, 64);
    if (lane == 0) { Ce = 1.0f; De = 0.0f; }
    const float h0 = h_prev[chain];
    float hs = fmaf(Ce, h0, De);
    float4 o;
    o.x = hs;
    hs = fmaf(q0.x, hs, q0.y); o.y = hs;
    hs = fmaf(q0.z, hs, q0.w); o.z = hs;
    hs = fmaf(q1.x, hs, q1.y); o.w = hs;
    *(float4*)&Hseg[(size_t)chain * SPB + lane * 4] = o;
}

// ---------------------------------------------------------------------------
// final apply: 1024 blocks (one per 32-t segment) x 256 thr x 2 h.
// Full-unroll nontemporal loads/stores (ext_vector types for the builtin).
// ---------------------------------------------------------------------------
__global__ __launch_bounds__(256)
void apply_scan(const unsigned int* __restrict__ cd,
                const float* __restrict__ Hseg,
                float* __restrict__ out)
{
    const int sg = blockIdx.x;            // global segment
    const int b  = sg >> 8;
    const int s  = sg & 255;
    const int h  = threadIdx.x * 2;
    float hs0 = Hseg[(size_t)(b * 512 + h)     * SPB + s];
    float hs1 = Hseg[(size_t)(b * 512 + h + 1) * SPB + s];
    const unsigned int* base = cd + (size_t)sg * SEG * H_ + h;
    float* ob = out + (size_t)sg * SEG * H_ + h;
    #pragma unroll
    for (int t = 0; t < SEG; ++t) {
        uint2e v = __builtin_nontemporal_load((const uint2e*)(base + (size_t)t * H_));
        hs0 = fmaf(bf_lo(v.x), hs0, bf_hi(v.x));
        hs1 = fmaf(bf_lo(v.y), hs1, bf_hi(v.y));
        float2e o; o.x = hs0; o.y = hs1;
        __builtin_nontemporal_store(o, (float2e*)(ob + (size_t)t * H_));
    }
}

// ---------------------------------------------------------------------------
extern "C" void kernel_launch(void* const* d_in, const int* in_sizes, int n_in,
                              void* d_out, int out_size, void* d_ws, size_t ws_size,
                              hipStream_t stream)
{
    const float* x      = (const float*)d_in[0];
    const float* h_prev = (const float*)d_in[1];
    const float* W_h    = (const float*)d_in[2];
    const float* b_h    = (const float*)d_in[3];
    const float* W_z    = (const float*)d_in[4];
    const float* b_z    = (const float*)d_in[5];
    float* out = (float*)d_out;

    // xbf lives in d_out (dead until apply_scan overwrites all of it)
    unsigned short* xbf = (unsigned short*)d_out;

    char* ws = (char*)d_ws;
    unsigned int* cd = (unsigned int*)ws;                       // 67.1 MB
    size_t cd_bytes = (size_t)M_ * H_ * 4;
    unsigned short* Wf = (unsigned short*)(ws + cd_bytes);      // 1 MB
    size_t wf_bytes = (size_t)2 * H_ * D_ * sizeof(unsigned short);
    float2* Sagg = (float2*)(ws + cd_bytes + wf_bytes);         // 2048*256*8 = 4 MB
    float*  Hseg = (float*)((char*)Sagg + (size_t)2048 * SPB * sizeof(float2)); // 2 MB

    // 0) convert inputs to bf16
    {
        int total = M_ * D_ / 4 + 2 * (H_ * D_ / 4);
        conv_all<<<dim3((total + 255) / 256), dim3(256), 0, stream>>>(x, W_z, W_h, xbf, Wf);
    }
    // 1) dual GEMM + activation + fused segment aggregates (chain-major Sagg)
    gemm_cd<<<dim3((M_ / 128) * (H_ / 64)), dim3(256), 0, stream>>>(
        xbf, Wf, b_z, b_h, cd, Sagg);
    // 2) inter-segment scan, wave-per-chain
    interseg<<<dim3(512), dim3(256), 0, stream>>>(h_prev, Sagg, Hseg);
    // 3) final apply -> d_out
    apply_scan<<<dim3(NSEG), dim3(256), 0, stream>>>(cd, Hseg, out);
}